// Round 1
// baseline (30.366 us; speedup 1.0000x reference)
//
#include <hip/hip_runtime.h>

#define K_TOTAL 32768
#define R_TOTAL 128
#define A_DIM   16

// ---------------------------------------------------------------------------
// Kernel 1: precompute per-(r,a) membership constants.
//   sort abcd -> a<=b<=c<=d, then store FMA-form constants:
//   rise = (x-a)/(b-a) = x*c0 + c1   with c0 =  1/(b-a), c1 = -a/(b-a)
//   fall = (d-x)/(d-c) = x*c2 + c3   with c2 = -1/(d-c), c3 =  d/(d-c)
// ---------------------------------------------------------------------------
__global__ __launch_bounds__(256) void fuzzy_pre(const float* __restrict__ abcd,
                                                 float4* __restrict__ tab) {
    int idx = blockIdx.x * 256 + threadIdx.x;           // (r*16 + a), 0..2047
    if (idx >= R_TOTAL * A_DIM) return;
    float4 v = ((const float4*)abcd)[idx];
    float v0 = v.x, v1 = v.y, v2 = v.z, v3 = v.w;
    float t;
    // 5-comparator sorting network for 4 elements
    t = fminf(v0, v1); v1 = fmaxf(v0, v1); v0 = t;
    t = fminf(v2, v3); v3 = fmaxf(v2, v3); v2 = t;
    t = fminf(v0, v2); v2 = fmaxf(v0, v2); v0 = t;
    t = fminf(v1, v3); v3 = fmaxf(v1, v3); v1 = t;
    t = fminf(v1, v2); v2 = fmaxf(v1, v2); v1 = t;
    // v0=a, v1=b, v2=c, v3=d
    float inv_ba = 1.0f / (v1 - v0);
    float inv_dc = 1.0f / (v3 - v2);
    float4 o;
    o.x =  inv_ba;
    o.y = -v0 * inv_ba;
    o.z = -inv_dc;
    o.w =  v3 * inv_dc;
    tab[idx] = o;
}

// ---------------------------------------------------------------------------
// Kernel 2: main. Block = 512 threads = 8 waves.
//   wave w (= r-chunk) handles rules [w*16, w*16+16) for 64 k's.
//   Rule constants are wave-uniform -> scalar (s_load) operand delivery.
//   LDS reduction across the 8 r-chunks, then out = num/(den+1e-13).
// ---------------------------------------------------------------------------
__global__ __launch_bounds__(512) void fuzzy_main(const float*  __restrict__ input,
                                                  const float4* __restrict__ tab,
                                                  const float*  __restrict__ rho,
                                                  float*        __restrict__ out) {
    __shared__ float num_s[8][64];
    __shared__ float den_s[8][64];

    const int t     = threadIdx.x;
    const int kk    = t & 63;
    // r-chunk id: wave-uniform by construction; readfirstlane makes the
    // compiler treat it (and all derived addresses) as scalar -> s_load.
    const int chunk = __builtin_amdgcn_readfirstlane(t >> 6);
    const int k     = blockIdx.x * 64 + kk;

    // Load this point's 16 coordinates (64B, aligned, once per thread).
    float x[A_DIM];
    const float4* xin = (const float4*)(input + k * A_DIM);
    {
        float4 x0 = xin[0], x1 = xin[1], x2 = xin[2], x3 = xin[3];
        x[0]=x0.x;  x[1]=x0.y;  x[2]=x0.z;  x[3]=x0.w;
        x[4]=x1.x;  x[5]=x1.y;  x[6]=x1.z;  x[7]=x1.w;
        x[8]=x2.x;  x[9]=x2.y;  x[10]=x2.z; x[11]=x2.w;
        x[12]=x3.x; x[13]=x3.y; x[14]=x3.z; x[15]=x3.w;
    }

    float num = 0.0f, den = 0.0f;
    const int r0 = chunk * 16;

    #pragma unroll
    for (int i = 0; i < 16; ++i) {
        const int r = r0 + i;
        const float4* __restrict__ tr = tab + r * A_DIM;
        const float*  __restrict__ rr = rho + r * (A_DIM + 1);

        float z = rr[A_DIM];           // bias
        float m[A_DIM];
        #pragma unroll
        for (int a = 0; a < A_DIM; ++a) {
            float4 c   = tr[a];
            float rise = fmaf(x[a], c.x, c.y);
            float fall = fmaf(x[a], c.z, c.w);
            float mm   = fminf(fminf(rise, fall), 1.0f);   // -> v_min3
            m[a]       = fmaxf(mm, 0.0f);
            z          = fmaf(x[a], rr[a], z);
        }
        // balanced product tree (log depth, 15 mults)
        float w = ((m[0] * m[1]) * (m[2]  * m[3]))  * ((m[4]  * m[5])  * (m[6]  * m[7])) ;
        w      *= ((m[8] * m[9]) * (m[10] * m[11])) * ((m[12] * m[13]) * (m[14] * m[15]));
        num = fmaf(z, w, num);
        den += w;
    }

    num_s[chunk][kk] = num;
    den_s[chunk][kk] = den;
    __syncthreads();

    if (t < 64) {
        float n = 0.0f, d = 0.0f;
        #pragma unroll
        for (int c = 0; c < 8; ++c) { n += num_s[c][t]; d += den_s[c][t]; }
        out[blockIdx.x * 64 + t] = n / (d + 1e-13f);
    }
}

// ---------------------------------------------------------------------------
extern "C" void kernel_launch(void* const* d_in, const int* in_sizes, int n_in,
                              void* d_out, int out_size, void* d_ws, size_t ws_size,
                              hipStream_t stream) {
    const float* input = (const float*)d_in[0];   // (K, A)   fp32
    const float* abcd  = (const float*)d_in[1];   // (R, A, 4) fp32
    const float* rho   = (const float*)d_in[2];   // (R, A+1) fp32
    float* out = (float*)d_out;                   // (K,) fp32
    float4* tab = (float4*)d_ws;                  // 32 KB scratch

    fuzzy_pre<<<(R_TOTAL * A_DIM + 255) / 256, 256, 0, stream>>>(abcd, tab);
    fuzzy_main<<<K_TOTAL / 64, 512, 0, stream>>>(input, tab, rho, out);
}